// Round 4
// baseline (764.328 us; speedup 1.0000x reference)
//
#include <hip/hip_runtime.h>

typedef unsigned short u16;
typedef unsigned int u32;

typedef __bf16 v8bf __attribute__((ext_vector_type(8)));
typedef float v4f __attribute__((ext_vector_type(4)));

#define N_TOK 8192
#define CDIM 512
#define HEADS 8
#define HD 64
#define LM 64
#define LSTRIDE 128
#define BHN 32
#define NCHUNK 16
#define SCALE 0.125f

__device__ __forceinline__ float b2f(u16 u) { return __uint_as_float(((u32)u) << 16); }
__device__ __forceinline__ u16 f2bf(float f) {
  u32 u = __float_as_uint(f);
  u += 0x7fffu + ((u >> 16) & 1u);
  return (u16)(u >> 16);
}

// ---------------------------------------------------------------------------
// GEMM: C[m][n] = sum_k A[m][k]*B[n][k] + bias[n]
// MODE 0: A = x (fp32), B = Wqkv (fp32); scatter bf16 to q/k/v [bh][n][d]
// MODE 1: A = attn (bf16), B = Wproj (fp32); store fp32 row-major [m][n]
// fp32 operands are converted to bf16 during LDS staging (RNE).
// 128x128 tile, BK=32, 256 threads = 4 waves (2x2 of 64x64), 16x16x32 MFMA.
// ---------------------------------------------------------------------------
template <int MODE>
__global__ __launch_bounds__(256) void gemm_bt(const float* __restrict__ Af,
                                               const u16* __restrict__ Ab,
                                               const float* __restrict__ Bf,
                                               const float* __restrict__ bias,
                                               u16* __restrict__ qo,
                                               u16* __restrict__ ko,
                                               u16* __restrict__ vo,
                                               float* __restrict__ outp) {
  __shared__ u16 As[128 * 32];
  __shared__ u16 Bs[128 * 32];
  const int K = 512;
  const int m0 = blockIdx.x * 128;
  const int n0 = blockIdx.y * 128;
  const int t = threadIdx.x;
  const int lane = t & 63, w = t >> 6;
  const int wm = w >> 1, wn = w & 1;
  const int quad = lane >> 4, lrow = lane & 15;

  v4f acc[4][4];
#pragma unroll
  for (int i = 0; i < 4; ++i)
#pragma unroll
    for (int j = 0; j < 4; ++j)
#pragma unroll
      for (int r = 0; r < 4; ++r) acc[i][j][r] = 0.f;

  for (int kt = 0; kt < K; kt += 32) {
    __syncthreads();
    // B (always fp32): 128x32 = 4096 floats, 256 threads x 4 float4 loads
#pragma unroll
    for (int p = 0; p < 4; ++p) {
      int lin = p * 256 + t;
      int row = lin >> 3, c4 = (lin & 7) * 4;
      float4 fb = *(const float4*)(Bf + (size_t)(n0 + row) * K + kt + c4);
      ushort4 hb = {f2bf(fb.x), f2bf(fb.y), f2bf(fb.z), f2bf(fb.w)};
      *(ushort4*)&Bs[row * 32 + c4] = hb;
    }
    if (MODE == 0) {  // A fp32
#pragma unroll
      for (int p = 0; p < 4; ++p) {
        int lin = p * 256 + t;
        int row = lin >> 3, c4 = (lin & 7) * 4;
        float4 fa = *(const float4*)(Af + (size_t)(m0 + row) * K + kt + c4);
        ushort4 ha = {f2bf(fa.x), f2bf(fa.y), f2bf(fa.z), f2bf(fa.w)};
        *(ushort4*)&As[row * 32 + c4] = ha;
      }
    } else {  // A bf16
#pragma unroll
      for (int p = 0; p < 2; ++p) {
        int lin = p * 256 + t;
        int row = lin >> 2, c8 = (lin & 3) * 8;
        *(uint4*)&As[row * 32 + c8] = *(const uint4*)(Ab + (size_t)(m0 + row) * K + kt + c8);
      }
    }
    __syncthreads();
    v8bf af[4], bf[4];
#pragma unroll
    for (int ti = 0; ti < 4; ++ti)
      af[ti] = *(const v8bf*)&As[(wm * 64 + ti * 16 + lrow) * 32 + quad * 8];
#pragma unroll
    for (int tj = 0; tj < 4; ++tj)
      bf[tj] = *(const v8bf*)&Bs[(wn * 64 + tj * 16 + lrow) * 32 + quad * 8];
#pragma unroll
    for (int ti = 0; ti < 4; ++ti)
#pragma unroll
      for (int tj = 0; tj < 4; ++tj)
        acc[ti][tj] = __builtin_amdgcn_mfma_f32_16x16x32_bf16(af[ti], bf[tj], acc[ti][tj], 0, 0, 0);
  }

  // epilogue: D layout col=lane&15, row=quad*4+reg (m89/m91-verified)
#pragma unroll
  for (int ti = 0; ti < 4; ++ti) {
#pragma unroll
    for (int tj = 0; tj < 4; ++tj) {
      int gn = n0 + wn * 64 + tj * 16 + lrow;
      float bv = bias[gn];
#pragma unroll
      for (int r = 0; r < 4; ++r) {
        int gm = m0 + wm * 64 + ti * 16 + quad * 4 + r;
        float val = acc[ti][tj][r] + bv;
        if (MODE == 0) {
          int tt = gn >> 9;          // 0=q 1=k 2=v
          int h = (gn >> 6) & 7;
          int d = gn & 63;
          int b = gm >> 13;
          int n = gm & 8191;
          size_t di = ((size_t)(b * HEADS + h) * N_TOK + n) * HD + d;
          u16* dst = (tt == 0) ? qo : (tt == 1) ? ko : vo;
          dst[di] = f2bf(val);
        } else {
          outp[(size_t)gm * CDIM + gn] = val;
        }
      }
    }
  }
}

// ---------------------------------------------------------------------------
// Fused kernel_3 chunk: for j-chunk jc (512 tokens), online-softmax over
// logits S[i][j] = scale * q_lm[i]·k[j], accumulate F = sum exp(S-m)·v.
// Emits unnormalized Fp[bh][jc][64][64], chunk max Mc, chunk sum Sc.
// ---------------------------------------------------------------------------
__global__ __launch_bounds__(256) void fpart(const u16* __restrict__ qb,
                                             const u16* __restrict__ kb,
                                             const u16* __restrict__ vb,
                                             float* __restrict__ Fp,
                                             float* __restrict__ Mc,
                                             float* __restrict__ Sc) {
  __shared__ float qlm[64 * 65];   // [i][d]
  __shared__ float ks[32 * 65];    // [j][d]
  __shared__ float vs[32 * 65];    // [j][d]
  __shared__ float Ps[64 * 33];    // [i][j]
  __shared__ float ms[64], ss[64], alphas[64], betas[64];
  const int jc = blockIdx.x, bh = blockIdx.y;
  const int t = threadIdx.x;
  const int ti = t >> 4, tj = t & 15;   // rows i=ti*4+a; S cols j=tj*2+b; F cols d=tj*4+b

#pragma unroll
  for (int p = 0; p < 16; ++p) {
    int idx = p * 256 + t;
    int i = idx >> 6, d = idx & 63;
    qlm[i * 65 + d] = b2f(qb[((size_t)bh * N_TOK + i * LSTRIDE) * HD + d]);
  }
  if (t < 64) { ms[t] = -3.0e38f; ss[t] = 0.f; }

  float F[4][4];
#pragma unroll
  for (int a = 0; a < 4; ++a)
#pragma unroll
    for (int b = 0; b < 4; ++b) F[a][b] = 0.f;

  for (int st = 0; st < 16; ++st) {
    __syncthreads();
#pragma unroll
    for (int p = 0; p < 8; ++p) {
      int idx = p * 256 + t;
      int j = idx >> 6, d = idx & 63;
      size_t g = ((size_t)bh * N_TOK + jc * 512 + st * 32 + j) * HD + d;
      ks[j * 65 + d] = b2f(kb[g]);
      vs[j * 65 + d] = b2f(vb[g]);
    }
    __syncthreads();
    float S[4][2];
#pragma unroll
    for (int a = 0; a < 4; ++a)
#pragma unroll
      for (int b = 0; b < 2; ++b) S[a][b] = 0.f;
    for (int d = 0; d < 64; ++d) {
      float qa[4], kv[2];
#pragma unroll
      for (int a = 0; a < 4; ++a) qa[a] = qlm[(ti * 4 + a) * 65 + d];
#pragma unroll
      for (int b = 0; b < 2; ++b) kv[b] = ks[(tj * 2 + b) * 65 + d];
#pragma unroll
      for (int a = 0; a < 4; ++a)
#pragma unroll
        for (int b = 0; b < 2; ++b) S[a][b] += qa[a] * kv[b];
    }
    float msub[4], rsum[4];
#pragma unroll
    for (int a = 0; a < 4; ++a) {
      S[a][0] *= SCALE; S[a][1] *= SCALE;
      float m = fmaxf(S[a][0], S[a][1]);
#pragma unroll
      for (int off = 8; off; off >>= 1) m = fmaxf(m, __shfl_xor(m, off));
      msub[a] = m;
      float p0 = expf(S[a][0] - m), p1 = expf(S[a][1] - m);
      Ps[(ti * 4 + a) * 33 + tj * 2 + 0] = p0;
      Ps[(ti * 4 + a) * 33 + tj * 2 + 1] = p1;
      float s = p0 + p1;
#pragma unroll
      for (int off = 8; off; off >>= 1) s += __shfl_xor(s, off);
      rsum[a] = s;
    }
    if (tj == 0) {
#pragma unroll
      for (int a = 0; a < 4; ++a) {
        int i = ti * 4 + a;
        float mo = ms[i];
        float mn = fmaxf(mo, msub[a]);
        float alpha = expf(mo - mn);
        float beta = expf(msub[a] - mn);
        ms[i] = mn;
        ss[i] = ss[i] * alpha + beta * rsum[a];
        alphas[i] = alpha;
        betas[i] = beta;
      }
    }
    __syncthreads();
#pragma unroll
    for (int a = 0; a < 4; ++a) {
      int i = ti * 4 + a;
      float al = alphas[i], be = betas[i];
      float tmp[4] = {0.f, 0.f, 0.f, 0.f};
      for (int jj = 0; jj < 32; ++jj) {
        float pv = Ps[i * 33 + jj];
#pragma unroll
        for (int b = 0; b < 4; ++b) tmp[b] += pv * vs[jj * 65 + tj * 4 + b];
      }
#pragma unroll
      for (int b = 0; b < 4; ++b) F[a][b] = F[a][b] * al + be * tmp[b];
    }
  }

  size_t base = (size_t)(bh * NCHUNK + jc) * 4096;
#pragma unroll
  for (int a = 0; a < 4; ++a)
#pragma unroll
    for (int b = 0; b < 4; ++b)
      Fp[base + (ti * 4 + a) * 64 + tj * 4 + b] = F[a][b];
  __syncthreads();
  if (t < 64) {
    Mc[(bh * NCHUNK + jc) * 64 + t] = ms[t];
    Sc[(bh * NCHUNK + jc) * 64 + t] = ss[t];
  }
}

// ---------------------------------------------------------------------------
// Per-(b,h): kernel_2 softmax, Newton-Schulz inverse (6 iters, reference op
// order: W=Z@M; Z=2Z-W@Z), F = combine chunks (log-sum-exp), T = Z @ F.
// ---------------------------------------------------------------------------
__global__ __launch_bounds__(256) void newton_t(const u16* __restrict__ qb,
                                                const u16* __restrict__ kb,
                                                const float* __restrict__ Fp,
                                                const float* __restrict__ Mc,
                                                const float* __restrict__ Sc,
                                                float* __restrict__ T) {
  __shared__ float Ms[4096];
  __shared__ float Z0s[4096];
  __shared__ float Ws[4096];
  __shared__ float Xs[4096];
  const int bh = blockIdx.x;
  const int t = threadIdx.x;
  const int lane = t & 63, w = t >> 6;
  const int ti = t >> 4, tj = t & 15;

#pragma unroll
  for (int p = 0; p < 16; ++p) {
    int idx = p * 256 + t;
    int i = idx >> 6, d = idx & 63;
    Ws[idx] = b2f(qb[((size_t)bh * N_TOK + i * LSTRIDE) * HD + d]);
    Xs[d * 64 + i] = b2f(kb[((size_t)bh * N_TOK + i * LSTRIDE) * HD + d]);
  }
  __syncthreads();

  {
    float a2[4][4];
#pragma unroll
    for (int a = 0; a < 4; ++a)
#pragma unroll
      for (int b = 0; b < 4; ++b) a2[a][b] = 0.f;
    for (int d = 0; d < 64; ++d) {
      float qa[4], kv[4];
#pragma unroll
      for (int a = 0; a < 4; ++a) qa[a] = Ws[(ti * 4 + a) * 64 + d];
#pragma unroll
      for (int b = 0; b < 4; ++b) kv[b] = Xs[d * 64 + tj * 4 + b];
#pragma unroll
      for (int a = 0; a < 4; ++a)
#pragma unroll
        for (int b = 0; b < 4; ++b) a2[a][b] += qa[a] * kv[b];
    }
    __syncthreads();
#pragma unroll
    for (int a = 0; a < 4; ++a)
#pragma unroll
      for (int b = 0; b < 4; ++b) Ms[(ti * 4 + a) * 64 + tj * 4 + b] = a2[a][b] * SCALE;
  }
  __syncthreads();

  for (int rr = 0; rr < 16; ++rr) {
    int i = w * 16 + rr;
    float vv = Ms[i * 64 + lane];
    float m = vv;
#pragma unroll
    for (int off = 32; off; off >>= 1) m = fmaxf(m, __shfl_xor(m, off));
    float e = expf(vv - m);
    float s = e;
#pragma unroll
    for (int off = 32; off; off >>= 1) s += __shfl_xor(s, off);
    Ms[i * 64 + lane] = e / s;
  }
  __syncthreads();

  float loc = 0.f;
#pragma unroll
  for (int p = 0; p < 16; ++p) {
    float v = Ms[p * 256 + t];
    loc += v * v;
  }
#pragma unroll
  for (int off = 32; off; off >>= 1) loc += __shfl_xor(loc, off);
  if (lane == 0) Z0s[w] = loc;
  __syncthreads();
  float fro = fmaxf(sqrtf(Z0s[0] + Z0s[1] + Z0s[2] + Z0s[3]), 1e-6f);
  float invden = 1.0f / (fro * fro);
  __syncthreads();

#pragma unroll
  for (int p = 0; p < 16; ++p) {
    int idx = p * 256 + t;
    int i = idx >> 6, j = idx & 63;
    Z0s[j * 64 + i] = Ms[idx] * invden;
  }
  __syncthreads();

  float* Z = Z0s;
  float* Zn = Xs;
  for (int it = 0; it < 6; ++it) {
    {  // Ws = Z @ M
      float a2[4][4];
#pragma unroll
      for (int a = 0; a < 4; ++a)
#pragma unroll
        for (int b = 0; b < 4; ++b) a2[a][b] = 0.f;
      for (int tt = 0; tt < 64; ++tt) {
        float za[4], mb[4];
#pragma unroll
        for (int a = 0; a < 4; ++a) za[a] = Z[(ti * 4 + a) * 64 + tt];
#pragma unroll
        for (int b = 0; b < 4; ++b) mb[b] = Ms[tt * 64 + tj * 4 + b];
#pragma unroll
        for (int a = 0; a < 4; ++a)
#pragma unroll
          for (int b = 0; b < 4; ++b) a2[a][b] += za[a] * mb[b];
      }
#pragma unroll
      for (int a = 0; a < 4; ++a)
#pragma unroll
        for (int b = 0; b < 4; ++b) Ws[(ti * 4 + a) * 64 + tj * 4 + b] = a2[a][b];
    }
    __syncthreads();
    {  // Zn = 2Z - Ws @ Z
      float a2[4][4];
#pragma unroll
      for (int a = 0; a < 4; ++a)
#pragma unroll
        for (int b = 0; b < 4; ++b) a2[a][b] = 0.f;
      for (int tt = 0; tt < 64; ++tt) {
        float wa[4], zb[4];
#pragma unroll
        for (int a = 0; a < 4; ++a) wa[a] = Ws[(ti * 4 + a) * 64 + tt];
#pragma unroll
        for (int b = 0; b < 4; ++b) zb[b] = Z[tt * 64 + tj * 4 + b];
#pragma unroll
        for (int a = 0; a < 4; ++a)
#pragma unroll
          for (int b = 0; b < 4; ++b) a2[a][b] += wa[a] * zb[b];
      }
#pragma unroll
      for (int a = 0; a < 4; ++a)
#pragma unroll
        for (int b = 0; b < 4; ++b)
          Zn[(ti * 4 + a) * 64 + tj * 4 + b] =
              2.f * Z[(ti * 4 + a) * 64 + tj * 4 + b] - a2[a][b];
    }
    __syncthreads();
    float* tmp = Z; Z = Zn; Zn = tmp;
  }

  float* wts = Ms;  // Ms dead -> chunk combine weights [jc][i]
  if (t < 64) {
    float M = -3.0e38f;
#pragma unroll
    for (int jc = 0; jc < NCHUNK; ++jc)
      M = fmaxf(M, Mc[(bh * NCHUNK + jc) * 64 + t]);
    float S = 0.f;
#pragma unroll
    for (int jc = 0; jc < NCHUNK; ++jc)
      S += expf(Mc[(bh * NCHUNK + jc) * 64 + t] - M) * Sc[(bh * NCHUNK + jc) * 64 + t];
    float invS = 1.0f / S;
#pragma unroll
    for (int jc = 0; jc < NCHUNK; ++jc)
      wts[jc * 64 + t] = expf(Mc[(bh * NCHUNK + jc) * 64 + t] - M) * invS;
  }
  __syncthreads();

#pragma unroll
  for (int p = 0; p < 16; ++p) {
    int idx = p * 256 + t;
    int i = idx >> 6;
    float sum = 0.f;
#pragma unroll
    for (int jc = 0; jc < NCHUNK; ++jc)
      sum += wts[jc * 64 + i] * Fp[(size_t)(bh * NCHUNK + jc) * 4096 + idx];
    Ws[idx] = sum;
  }
  __syncthreads();

  {
    float a2[4][4];
#pragma unroll
    for (int a = 0; a < 4; ++a)
#pragma unroll
      for (int b = 0; b < 4; ++b) a2[a][b] = 0.f;
    for (int tt = 0; tt < 64; ++tt) {
      float za[4], fb[4];
#pragma unroll
      for (int a = 0; a < 4; ++a) za[a] = Z[(ti * 4 + a) * 64 + tt];
#pragma unroll
      for (int b = 0; b < 4; ++b) fb[b] = Ws[tt * 64 + tj * 4 + b];
#pragma unroll
      for (int a = 0; a < 4; ++a)
#pragma unroll
        for (int b = 0; b < 4; ++b) a2[a][b] += za[a] * fb[b];
    }
#pragma unroll
    for (int a = 0; a < 4; ++a)
#pragma unroll
      for (int b = 0; b < 4; ++b)
        T[(size_t)bh * 4096 + (ti * 4 + a) * 64 + tj * 4 + b] = a2[a][b];
  }
}

// ---------------------------------------------------------------------------
// Fused kernel_1 + @T: per row n, logits over 64 landmarks -> wave softmax ->
// out[n][d] = sum_j p_j * T[j][d], stored bf16 in [B][N][C] layout.
// R3 restructure: 128 rows/block (32/wave), padded LDS (stride 65 -> zero
// bank conflicts), ONE barrier per block; q via wave-uniform broadcast loads,
// p broadcast via __shfl — no barriers in the row loop.
// ---------------------------------------------------------------------------
__global__ __launch_bounds__(256) void attn_out_k(const u16* __restrict__ qb,
                                                  const u16* __restrict__ kb,
                                                  const float* __restrict__ T,
                                                  u16* __restrict__ ao) {
  __shared__ float klmT[64 * 65];  // [d][j] padded
  __shared__ float Ts[64 * 65];    // [j][d] padded
  const int bh = blockIdx.y;
  const int b = bh >> 3, h = bh & 7;
  const int t = threadIdx.x;
  const int lane = t & 63, w = t >> 6;
#pragma unroll
  for (int p = 0; p < 16; ++p) {
    int idx = p * 256 + t;
    int i = idx >> 6, d = idx & 63;
    klmT[d * 65 + i] = b2f(kb[((size_t)bh * N_TOK + i * LSTRIDE) * HD + d]);
    Ts[idx + (idx >> 6)] = T[(size_t)bh * 4096 + idx];  // Ts[i*65+d]
  }
  __syncthreads();

  for (int r = 0; r < 32; ++r) {
    int n = blockIdx.x * 128 + w * 32 + r;
    const u16* qrow = qb + ((size_t)bh * N_TOK + n) * HD;
    float l0 = 0.f, l1 = 0.f;
#pragma unroll
    for (int c = 0; c < 8; ++c) {
      uint4 q4 = *(const uint4*)(qrow + c * 8);  // wave-uniform broadcast, 8 bf16
      u32 qw[4] = {q4.x, q4.y, q4.z, q4.w};
#pragma unroll
      for (int e = 0; e < 4; ++e) {
        float qlo = __uint_as_float(qw[e] << 16);
        float qhi = __uint_as_float(qw[e] & 0xffff0000u);
        int d = c * 8 + e * 2;
        l0 += qlo * klmT[d * 65 + lane];
        l1 += qhi * klmT[(d + 1) * 65 + lane];
      }
    }
    float l = (l0 + l1) * SCALE;
    float m = l;
#pragma unroll
    for (int off = 32; off; off >>= 1) m = fmaxf(m, __shfl_xor(m, off));
    float e = expf(l - m);
    float s = e;
#pragma unroll
    for (int off = 32; off; off >>= 1) s += __shfl_xor(s, off);
    float pv = e / s;
    float o0 = 0.f, o1 = 0.f;
#pragma unroll
    for (int j = 0; j < 64; j += 2) {
      o0 += __shfl(pv, j) * Ts[j * 65 + lane];
      o1 += __shfl(pv, j + 1) * Ts[(j + 1) * 65 + lane];
    }
    ao[((size_t)(b * N_TOK + n)) * CDIM + h * HD + lane] = f2bf(o0 + o1);
  }
}

__global__ void ws_too_small_sentinel(float* out) {
  if (threadIdx.x == 0 && blockIdx.x == 0) out[0] = 1.0f;
}

// ---------------------------------------------------------------------------
// Workspace: q/k/v bf16 (32 MiB each), Fp fp32 8 MiB, Mc/Sc/T small.
// attn (bf16, 32 MiB) aliases v (dead after fpart). Total ~105 MiB.
// ---------------------------------------------------------------------------
static constexpr size_t SZ_QKV = (size_t)BHN * N_TOK * HD * 2;        // 32 MiB
static constexpr size_t OFF_Q = 0;
static constexpr size_t OFF_K = OFF_Q + SZ_QKV;
static constexpr size_t OFF_V = OFF_K + SZ_QKV;
static constexpr size_t OFF_FP = OFF_V + SZ_QKV;
static constexpr size_t SZ_FP = (size_t)BHN * NCHUNK * 4096 * 4;      // 8 MiB
static constexpr size_t OFF_MC = OFF_FP + SZ_FP;
static constexpr size_t SZ_MS = (size_t)BHN * NCHUNK * 64 * 4;        // 128 KiB
static constexpr size_t OFF_SC = OFF_MC + SZ_MS;
static constexpr size_t OFF_T = OFF_SC + SZ_MS;
static constexpr size_t OFF_END = OFF_T + (size_t)BHN * 4096 * 4;     // ~105 MiB

extern "C" void kernel_launch(void* const* d_in, const int* in_sizes, int n_in,
                              void* d_out, int out_size, void* d_ws, size_t ws_size,
                              hipStream_t stream) {
  const float* x = (const float*)d_in[0];
  const float* Wqkv = (const float*)d_in[1];
  const float* bqkv = (const float*)d_in[2];
  const float* Wproj = (const float*)d_in[3];
  const float* bproj = (const float*)d_in[4];
  float* out = (float*)d_out;
  char* ws = (char*)d_ws;
  if (ws_size < OFF_END) {  // diagnostic: absmax ~= 1 next round means ws too small
    ws_too_small_sentinel<<<1, 64, 0, stream>>>(out);
    return;
  }

  u16* qb = (u16*)(ws + OFF_Q);
  u16* kb = (u16*)(ws + OFF_K);
  u16* vb = (u16*)(ws + OFF_V);
  float* Fp = (float*)(ws + OFF_FP);
  float* Mc = (float*)(ws + OFF_MC);
  float* Sc = (float*)(ws + OFF_SC);
  float* T = (float*)(ws + OFF_T);
  u16* attn = (u16*)(ws + OFF_V);  // alias: v dead after fpart

  gemm_bt<0><<<dim3(256, 12), 256, 0, stream>>>(x, nullptr, Wqkv, bqkv, qb, kb, vb, nullptr);
  fpart<<<dim3(NCHUNK, BHN), 256, 0, stream>>>(qb, kb, vb, Fp, Mc, Sc);
  newton_t<<<dim3(BHN), 256, 0, stream>>>(qb, kb, Fp, Mc, Sc, T);
  attn_out_k<<<dim3(64, BHN), 256, 0, stream>>>(qb, kb, T, attn);
  gemm_bt<1><<<dim3(256, 4), 256, 0, stream>>>(nullptr, attn, Wproj, bproj, nullptr, nullptr, nullptr, out);
}

// Round 5
// 515.581 us; speedup vs baseline: 1.4825x; 1.4825x over previous
//
#include <hip/hip_runtime.h>

typedef unsigned short u16;
typedef unsigned int u32;

typedef __bf16 v8bf __attribute__((ext_vector_type(8)));
typedef float v4f __attribute__((ext_vector_type(4)));

#define N_TOK 8192
#define CDIM 512
#define HEADS 8
#define HD 64
#define LM 64
#define LSTRIDE 128
#define BHN 32
#define NCHUNK 16
#define SCALE 0.125f

__device__ __forceinline__ float b2f(u16 u) { return __uint_as_float(((u32)u) << 16); }
__device__ __forceinline__ u16 f2bf(float f) {
  u32 u = __float_as_uint(f);
  u += 0x7fffu + ((u >> 16) & 1u);
  return (u16)(u >> 16);
}

// ---------------------------------------------------------------------------
// GEMM: C[m][n] = sum_k A[m][k]*B[n][k] + bias[n]
// MODE 0: A = x (fp32), B = Wqkv (fp32); scatter bf16 to q/k/v [bh][n][d]
// MODE 1: A = attn (bf16), B = Wproj (fp32); store fp32 row-major [m][n]
// ---------------------------------------------------------------------------
template <int MODE>
__global__ __launch_bounds__(256) void gemm_bt(const float* __restrict__ Af,
                                               const u16* __restrict__ Ab,
                                               const float* __restrict__ Bf,
                                               const float* __restrict__ bias,
                                               u16* __restrict__ qo,
                                               u16* __restrict__ ko,
                                               u16* __restrict__ vo,
                                               float* __restrict__ outp) {
  __shared__ u16 As[128 * 32];
  __shared__ u16 Bs[128 * 32];
  const int K = 512;
  const int m0 = blockIdx.x * 128;
  const int n0 = blockIdx.y * 128;
  const int t = threadIdx.x;
  const int lane = t & 63, w = t >> 6;
  const int wm = w >> 1, wn = w & 1;
  const int quad = lane >> 4, lrow = lane & 15;

  v4f acc[4][4];
#pragma unroll
  for (int i = 0; i < 4; ++i)
#pragma unroll
    for (int j = 0; j < 4; ++j)
#pragma unroll
      for (int r = 0; r < 4; ++r) acc[i][j][r] = 0.f;

  for (int kt = 0; kt < K; kt += 32) {
    __syncthreads();
#pragma unroll
    for (int p = 0; p < 4; ++p) {
      int lin = p * 256 + t;
      int row = lin >> 3, c4 = (lin & 7) * 4;
      float4 fb = *(const float4*)(Bf + (size_t)(n0 + row) * K + kt + c4);
      ushort4 hb = {f2bf(fb.x), f2bf(fb.y), f2bf(fb.z), f2bf(fb.w)};
      *(ushort4*)&Bs[row * 32 + c4] = hb;
    }
    if (MODE == 0) {  // A fp32
#pragma unroll
      for (int p = 0; p < 4; ++p) {
        int lin = p * 256 + t;
        int row = lin >> 3, c4 = (lin & 7) * 4;
        float4 fa = *(const float4*)(Af + (size_t)(m0 + row) * K + kt + c4);
        ushort4 ha = {f2bf(fa.x), f2bf(fa.y), f2bf(fa.z), f2bf(fa.w)};
        *(ushort4*)&As[row * 32 + c4] = ha;
      }
    } else {  // A bf16
#pragma unroll
      for (int p = 0; p < 2; ++p) {
        int lin = p * 256 + t;
        int row = lin >> 2, c8 = (lin & 3) * 8;
        *(uint4*)&As[row * 32 + c8] = *(const uint4*)(Ab + (size_t)(m0 + row) * K + kt + c8);
      }
    }
    __syncthreads();
    v8bf af[4], bf[4];
#pragma unroll
    for (int ti = 0; ti < 4; ++ti)
      af[ti] = *(const v8bf*)&As[(wm * 64 + ti * 16 + lrow) * 32 + quad * 8];
#pragma unroll
    for (int tj = 0; tj < 4; ++tj)
      bf[tj] = *(const v8bf*)&Bs[(wn * 64 + tj * 16 + lrow) * 32 + quad * 8];
#pragma unroll
    for (int ti = 0; ti < 4; ++ti)
#pragma unroll
      for (int tj = 0; tj < 4; ++tj)
        acc[ti][tj] = __builtin_amdgcn_mfma_f32_16x16x32_bf16(af[ti], bf[tj], acc[ti][tj], 0, 0, 0);
  }

#pragma unroll
  for (int ti = 0; ti < 4; ++ti) {
#pragma unroll
    for (int tj = 0; tj < 4; ++tj) {
      int gn = n0 + wn * 64 + tj * 16 + lrow;
      float bv = bias[gn];
#pragma unroll
      for (int r = 0; r < 4; ++r) {
        int gm = m0 + wm * 64 + ti * 16 + quad * 4 + r;
        float val = acc[ti][tj][r] + bv;
        if (MODE == 0) {
          int tt = gn >> 9;          // 0=q 1=k 2=v
          int h = (gn >> 6) & 7;
          int d = gn & 63;
          int b = gm >> 13;
          int n = gm & 8191;
          size_t di = ((size_t)(b * HEADS + h) * N_TOK + n) * HD + d;
          u16* dst = (tt == 0) ? qo : (tt == 1) ? ko : vo;
          dst[di] = f2bf(val);
        } else {
          outp[(size_t)gm * CDIM + gn] = val;
        }
      }
    }
  }
}

// ---------------------------------------------------------------------------
// Fused kernel_3 chunk (unchanged): online-softmax over j-chunk of 512,
// emits unnormalized Fp, chunk max Mc, chunk sum Sc.
// ---------------------------------------------------------------------------
__global__ __launch_bounds__(256) void fpart(const u16* __restrict__ qb,
                                             const u16* __restrict__ kb,
                                             const u16* __restrict__ vb,
                                             float* __restrict__ Fp,
                                             float* __restrict__ Mc,
                                             float* __restrict__ Sc) {
  __shared__ float qlm[64 * 65];
  __shared__ float ks[32 * 65];
  __shared__ float vs[32 * 65];
  __shared__ float Ps[64 * 33];
  __shared__ float ms[64], ss[64], alphas[64], betas[64];
  const int jc = blockIdx.x, bh = blockIdx.y;
  const int t = threadIdx.x;
  const int ti = t >> 4, tj = t & 15;

#pragma unroll
  for (int p = 0; p < 16; ++p) {
    int idx = p * 256 + t;
    int i = idx >> 6, d = idx & 63;
    qlm[i * 65 + d] = b2f(qb[((size_t)bh * N_TOK + i * LSTRIDE) * HD + d]);
  }
  if (t < 64) { ms[t] = -3.0e38f; ss[t] = 0.f; }

  float F[4][4];
#pragma unroll
  for (int a = 0; a < 4; ++a)
#pragma unroll
    for (int b = 0; b < 4; ++b) F[a][b] = 0.f;

  for (int st = 0; st < 16; ++st) {
    __syncthreads();
#pragma unroll
    for (int p = 0; p < 8; ++p) {
      int idx = p * 256 + t;
      int j = idx >> 6, d = idx & 63;
      size_t g = ((size_t)bh * N_TOK + jc * 512 + st * 32 + j) * HD + d;
      ks[j * 65 + d] = b2f(kb[g]);
      vs[j * 65 + d] = b2f(vb[g]);
    }
    __syncthreads();
    float S[4][2];
#pragma unroll
    for (int a = 0; a < 4; ++a)
#pragma unroll
      for (int b = 0; b < 2; ++b) S[a][b] = 0.f;
    for (int d = 0; d < 64; ++d) {
      float qa[4], kv[2];
#pragma unroll
      for (int a = 0; a < 4; ++a) qa[a] = qlm[(ti * 4 + a) * 65 + d];
#pragma unroll
      for (int b = 0; b < 2; ++b) kv[b] = ks[(tj * 2 + b) * 65 + d];
#pragma unroll
      for (int a = 0; a < 4; ++a)
#pragma unroll
        for (int b = 0; b < 2; ++b) S[a][b] += qa[a] * kv[b];
    }
    float msub[4], rsum[4];
#pragma unroll
    for (int a = 0; a < 4; ++a) {
      S[a][0] *= SCALE; S[a][1] *= SCALE;
      float m = fmaxf(S[a][0], S[a][1]);
#pragma unroll
      for (int off = 8; off; off >>= 1) m = fmaxf(m, __shfl_xor(m, off));
      msub[a] = m;
      float p0 = expf(S[a][0] - m), p1 = expf(S[a][1] - m);
      Ps[(ti * 4 + a) * 33 + tj * 2 + 0] = p0;
      Ps[(ti * 4 + a) * 33 + tj * 2 + 1] = p1;
      float s = p0 + p1;
#pragma unroll
      for (int off = 8; off; off >>= 1) s += __shfl_xor(s, off);
      rsum[a] = s;
    }
    if (tj == 0) {
#pragma unroll
      for (int a = 0; a < 4; ++a) {
        int i = ti * 4 + a;
        float mo = ms[i];
        float mn = fmaxf(mo, msub[a]);
        float alpha = expf(mo - mn);
        float beta = expf(msub[a] - mn);
        ms[i] = mn;
        ss[i] = ss[i] * alpha + beta * rsum[a];
        alphas[i] = alpha;
        betas[i] = beta;
      }
    }
    __syncthreads();
#pragma unroll
    for (int a = 0; a < 4; ++a) {
      int i = ti * 4 + a;
      float al = alphas[i], be = betas[i];
      float tmp[4] = {0.f, 0.f, 0.f, 0.f};
      for (int jj = 0; jj < 32; ++jj) {
        float pv = Ps[i * 33 + jj];
#pragma unroll
        for (int b = 0; b < 4; ++b) tmp[b] += pv * vs[jj * 65 + tj * 4 + b];
      }
#pragma unroll
      for (int b = 0; b < 4; ++b) F[a][b] = F[a][b] * al + be * tmp[b];
    }
  }

  size_t base = (size_t)(bh * NCHUNK + jc) * 4096;
#pragma unroll
  for (int a = 0; a < 4; ++a)
#pragma unroll
    for (int b = 0; b < 4; ++b)
      Fp[base + (ti * 4 + a) * 64 + tj * 4 + b] = F[a][b];
  __syncthreads();
  if (t < 64) {
    Mc[(bh * NCHUNK + jc) * 64 + t] = ms[t];
    Sc[(bh * NCHUNK + jc) * 64 + t] = ss[t];
  }
}

// ---------------------------------------------------------------------------
// Per-(b,h): kernel_2 softmax, Newton-Schulz inverse, chunk combine, T = Z@F.
// R4: epilogue now writes Tt = T^T in bf16 [bh][d][j] for the MFMA attn_out.
// ---------------------------------------------------------------------------
__global__ __launch_bounds__(256) void newton_t(const u16* __restrict__ qb,
                                                const u16* __restrict__ kb,
                                                const float* __restrict__ Fp,
                                                const float* __restrict__ Mc,
                                                const float* __restrict__ Sc,
                                                u16* __restrict__ Tt) {
  __shared__ float Ms[4096];
  __shared__ float Z0s[4096];
  __shared__ float Ws[4096];
  __shared__ float Xs[4096];
  const int bh = blockIdx.x;
  const int t = threadIdx.x;
  const int lane = t & 63, w = t >> 6;
  const int ti = t >> 4, tj = t & 15;

#pragma unroll
  for (int p = 0; p < 16; ++p) {
    int idx = p * 256 + t;
    int i = idx >> 6, d = idx & 63;
    Ws[idx] = b2f(qb[((size_t)bh * N_TOK + i * LSTRIDE) * HD + d]);
    Xs[d * 64 + i] = b2f(kb[((size_t)bh * N_TOK + i * LSTRIDE) * HD + d]);
  }
  __syncthreads();

  {
    float a2[4][4];
#pragma unroll
    for (int a = 0; a < 4; ++a)
#pragma unroll
      for (int b = 0; b < 4; ++b) a2[a][b] = 0.f;
    for (int d = 0; d < 64; ++d) {
      float qa[4], kv[4];
#pragma unroll
      for (int a = 0; a < 4; ++a) qa[a] = Ws[(ti * 4 + a) * 64 + d];
#pragma unroll
      for (int b = 0; b < 4; ++b) kv[b] = Xs[d * 64 + tj * 4 + b];
#pragma unroll
      for (int a = 0; a < 4; ++a)
#pragma unroll
        for (int b = 0; b < 4; ++b) a2[a][b] += qa[a] * kv[b];
    }
    __syncthreads();
#pragma unroll
    for (int a = 0; a < 4; ++a)
#pragma unroll
      for (int b = 0; b < 4; ++b) Ms[(ti * 4 + a) * 64 + tj * 4 + b] = a2[a][b] * SCALE;
  }
  __syncthreads();

  for (int rr = 0; rr < 16; ++rr) {
    int i = w * 16 + rr;
    float vv = Ms[i * 64 + lane];
    float m = vv;
#pragma unroll
    for (int off = 32; off; off >>= 1) m = fmaxf(m, __shfl_xor(m, off));
    float e = expf(vv - m);
    float s = e;
#pragma unroll
    for (int off = 32; off; off >>= 1) s += __shfl_xor(s, off);
    Ms[i * 64 + lane] = e / s;
  }
  __syncthreads();

  float loc = 0.f;
#pragma unroll
  for (int p = 0; p < 16; ++p) {
    float v = Ms[p * 256 + t];
    loc += v * v;
  }
#pragma unroll
  for (int off = 32; off; off >>= 1) loc += __shfl_xor(loc, off);
  if (lane == 0) Z0s[w] = loc;
  __syncthreads();
  float fro = fmaxf(sqrtf(Z0s[0] + Z0s[1] + Z0s[2] + Z0s[3]), 1e-6f);
  float invden = 1.0f / (fro * fro);
  __syncthreads();

#pragma unroll
  for (int p = 0; p < 16; ++p) {
    int idx = p * 256 + t;
    int i = idx >> 6, j = idx & 63;
    Z0s[j * 64 + i] = Ms[idx] * invden;
  }
  __syncthreads();

  float* Z = Z0s;
  float* Zn = Xs;
  for (int it = 0; it < 6; ++it) {
    {  // Ws = Z @ M
      float a2[4][4];
#pragma unroll
      for (int a = 0; a < 4; ++a)
#pragma unroll
        for (int b = 0; b < 4; ++b) a2[a][b] = 0.f;
      for (int tt = 0; tt < 64; ++tt) {
        float za[4], mb[4];
#pragma unroll
        for (int a = 0; a < 4; ++a) za[a] = Z[(ti * 4 + a) * 64 + tt];
#pragma unroll
        for (int b = 0; b < 4; ++b) mb[b] = Ms[tt * 64 + tj * 4 + b];
#pragma unroll
        for (int a = 0; a < 4; ++a)
#pragma unroll
          for (int b = 0; b < 4; ++b) a2[a][b] += za[a] * mb[b];
      }
#pragma unroll
      for (int a = 0; a < 4; ++a)
#pragma unroll
        for (int b = 0; b < 4; ++b) Ws[(ti * 4 + a) * 64 + tj * 4 + b] = a2[a][b];
    }
    __syncthreads();
    {  // Zn = 2Z - Ws @ Z
      float a2[4][4];
#pragma unroll
      for (int a = 0; a < 4; ++a)
#pragma unroll
        for (int b = 0; b < 4; ++b) a2[a][b] = 0.f;
      for (int tt = 0; tt < 64; ++tt) {
        float wa[4], zb[4];
#pragma unroll
        for (int a = 0; a < 4; ++a) wa[a] = Ws[(ti * 4 + a) * 64 + tt];
#pragma unroll
        for (int b = 0; b < 4; ++b) zb[b] = Z[tt * 64 + tj * 4 + b];
#pragma unroll
        for (int a = 0; a < 4; ++a)
#pragma unroll
          for (int b = 0; b < 4; ++b) a2[a][b] += wa[a] * zb[b];
      }
#pragma unroll
      for (int a = 0; a < 4; ++a)
#pragma unroll
        for (int b = 0; b < 4; ++b)
          Zn[(ti * 4 + a) * 64 + tj * 4 + b] =
              2.f * Z[(ti * 4 + a) * 64 + tj * 4 + b] - a2[a][b];
    }
    __syncthreads();
    float* tmp = Z; Z = Zn; Zn = tmp;
  }

  float* wts = Ms;  // Ms dead -> chunk combine weights [jc][i]
  if (t < 64) {
    float M = -3.0e38f;
#pragma unroll
    for (int jc = 0; jc < NCHUNK; ++jc)
      M = fmaxf(M, Mc[(bh * NCHUNK + jc) * 64 + t]);
    float S = 0.f;
#pragma unroll
    for (int jc = 0; jc < NCHUNK; ++jc)
      S += expf(Mc[(bh * NCHUNK + jc) * 64 + t] - M) * Sc[(bh * NCHUNK + jc) * 64 + t];
    float invS = 1.0f / S;
#pragma unroll
    for (int jc = 0; jc < NCHUNK; ++jc)
      wts[jc * 64 + t] = expf(Mc[(bh * NCHUNK + jc) * 64 + t] - M) * invS;
  }
  __syncthreads();

#pragma unroll
  for (int p = 0; p < 16; ++p) {
    int idx = p * 256 + t;
    int i = idx >> 6;
    float sum = 0.f;
#pragma unroll
    for (int jc = 0; jc < NCHUNK; ++jc)
      sum += wts[jc * 64 + i] * Fp[(size_t)(bh * NCHUNK + jc) * 4096 + idx];
    Ws[idx] = sum;
  }
  __syncthreads();

  {
    float a2[4][4];
#pragma unroll
    for (int a = 0; a < 4; ++a)
#pragma unroll
      for (int b = 0; b < 4; ++b) a2[a][b] = 0.f;
    for (int tt = 0; tt < 64; ++tt) {
      float za[4], fb[4];
#pragma unroll
      for (int a = 0; a < 4; ++a) za[a] = Z[(ti * 4 + a) * 64 + tt];
#pragma unroll
      for (int b = 0; b < 4; ++b) fb[b] = Ws[tt * 64 + tj * 4 + b];
#pragma unroll
      for (int a = 0; a < 4; ++a)
#pragma unroll
        for (int b = 0; b < 4; ++b) a2[a][b] += za[a] * fb[b];
    }
    // Tt[bh][d][j] bf16: T[i][d] -> Tt[d*64 + i]
#pragma unroll
    for (int a = 0; a < 4; ++a)
#pragma unroll
      for (int b = 0; b < 4; ++b)
        Tt[(size_t)bh * 4096 + (size_t)(tj * 4 + b) * 64 + (ti * 4 + a)] = f2bf(a2[a][b]);
  }
}

// ---------------------------------------------------------------------------
// R4 MFMA attn_out: per 16-token tile: S^T = klm @ q^T (MFMA), in-register
// softmax (cross-quad shfl), P through per-wave swizzled LDS (no barrier),
// out = P @ Tt (MFMA). klm/Tt fragments register-resident per block.
// LDS ops: ~12 per 16 tokens (vs ~192/token in R3) — kills the LDS-pipe bound.
// ---------------------------------------------------------------------------
__global__ __launch_bounds__(256) void attn_out_k(const u16* __restrict__ qb,
                                                  const u16* __restrict__ kb,
                                                  const u16* __restrict__ Tt,
                                                  u16* __restrict__ ao) {
  __shared__ __align__(16) u16 Pl[4][1024];   // per-wave 16 tok x 64 j bf16 (swizzled)
  const int bh = blockIdx.y;
  const int b = bh >> 3, h = bh & 7;
  const int t = threadIdx.x;
  const int lane = t & 63, w = t >> 6;
  const int col = lane & 15, quad = lane >> 4;
  const int rot = (col & 7) * 8;              // u16 units; 16B granules

  // Resident fragments: klm A-frags (A[m=j][k=d]) and Tt B-frags (B[n=d][k=j])
  v8bf kfr[4][2], tfr[4][2];
#pragma unroll
  for (int tj = 0; tj < 4; ++tj)
#pragma unroll
    for (int kh = 0; kh < 2; ++kh)
      kfr[tj][kh] = *(const v8bf*)(kb + ((size_t)bh * N_TOK + (size_t)(tj * 16 + col) * LSTRIDE) * HD + kh * 32 + quad * 8);
#pragma unroll
  for (int td = 0; td < 4; ++td)
#pragma unroll
    for (int jh = 0; jh < 2; ++jh)
      tfr[td][jh] = *(const v8bf*)(Tt + (size_t)bh * 4096 + (size_t)(td * 16 + col) * 64 + jh * 32 + quad * 8);

  u16* Pw = &Pl[w][0];

  for (int tile = 0; tile < 4; ++tile) {
    const int n0 = blockIdx.x * 256 + w * 64 + tile * 16;
    // q B-frags direct from global: B[n=tok][k=d]
    v8bf qf[2];
#pragma unroll
    for (int kh = 0; kh < 2; ++kh)
      qf[kh] = *(const v8bf*)(qb + ((size_t)bh * N_TOK + n0 + col) * HD + kh * 32 + quad * 8);

    // S^T[j][tok]: 4 j-tiles, D row = j_local = quad*4+r, D col = tok = col
    v4f S[4];
#pragma unroll
    for (int tj = 0; tj < 4; ++tj) {
#pragma unroll
      for (int r = 0; r < 4; ++r) S[tj][r] = 0.f;
#pragma unroll
      for (int kh = 0; kh < 2; ++kh)
        S[tj] = __builtin_amdgcn_mfma_f32_16x16x32_bf16(kfr[tj][kh], qf[kh], S[tj], 0, 0, 0);
    }

    // softmax over j (16 per-lane values + cross-quad reduce)
    float mx = -3.0e38f;
#pragma unroll
    for (int tj = 0; tj < 4; ++tj)
#pragma unroll
      for (int r = 0; r < 4; ++r) {
        S[tj][r] *= SCALE;
        mx = fmaxf(mx, S[tj][r]);
      }
    mx = fmaxf(mx, __shfl_xor(mx, 16));
    mx = fmaxf(mx, __shfl_xor(mx, 32));
    float sum = 0.f;
#pragma unroll
    for (int tj = 0; tj < 4; ++tj)
#pragma unroll
      for (int r = 0; r < 4; ++r) {
        S[tj][r] = __expf(S[tj][r] - mx);
        sum += S[tj][r];
      }
    sum += __shfl_xor(sum, 16);
    sum += __shfl_xor(sum, 32);
    float inv = 1.0f / sum;

    // P[tok][j] bf16 into per-wave LDS (swizzled rows; same-wave RAW, no barrier)
#pragma unroll
    for (int tj = 0; tj < 4; ++tj) {
      u32 lo = (u32)f2bf(S[tj][0] * inv) | ((u32)f2bf(S[tj][1] * inv) << 16);
      u32 hi = (u32)f2bf(S[tj][2] * inv) | ((u32)f2bf(S[tj][3] * inv) << 16);
      uint2 pk = {lo, hi};
      *(uint2*)&Pw[col * 64 + ((tj * 16 + quad * 4 + rot) & 63)] = pk;
    }
    // A-frags: A[m=tok=col][k=j=quad*8+..]
    v8bf pf[2];
#pragma unroll
    for (int jh = 0; jh < 2; ++jh)
      pf[jh] = *(const v8bf*)&Pw[col * 64 + ((jh * 32 + quad * 8 + rot) & 63)];

    // out = P @ Tt: D2 row = tok_local = quad*4+r, col = d = td*16+col
    v4f O[4];
#pragma unroll
    for (int td = 0; td < 4; ++td) {
#pragma unroll
      for (int r = 0; r < 4; ++r) O[td][r] = 0.f;
#pragma unroll
      for (int jh = 0; jh < 2; ++jh)
        O[td] = __builtin_amdgcn_mfma_f32_16x16x32_bf16(pf[jh], tfr[td][jh], O[td], 0, 0, 0);
    }
#pragma unroll
    for (int td = 0; td < 4; ++td)
#pragma unroll
      for (int r = 0; r < 4; ++r) {
        int n = n0 + quad * 4 + r;
        ao[((size_t)(b * N_TOK + n)) * CDIM + h * HD + td * 16 + col] = f2bf(O[td][r]);
      }
  }
}

__global__ void ws_too_small_sentinel(float* out) {
  if (threadIdx.x == 0 && blockIdx.x == 0) out[0] = 1.0f;
}

// ---------------------------------------------------------------------------
// Workspace: q/k/v bf16 (32 MiB each), Fp fp32 8 MiB, Mc/Sc small, Tt bf16.
// attn (bf16, 32 MiB) aliases v (dead after fpart). Total ~105 MiB.
// ---------------------------------------------------------------------------
static constexpr size_t SZ_QKV = (size_t)BHN * N_TOK * HD * 2;        // 32 MiB
static constexpr size_t OFF_Q = 0;
static constexpr size_t OFF_K = OFF_Q + SZ_QKV;
static constexpr size_t OFF_V = OFF_K + SZ_QKV;
static constexpr size_t OFF_FP = OFF_V + SZ_QKV;
static constexpr size_t SZ_FP = (size_t)BHN * NCHUNK * 4096 * 4;      // 8 MiB
static constexpr size_t OFF_MC = OFF_FP + SZ_FP;
static constexpr size_t SZ_MS = (size_t)BHN * NCHUNK * 64 * 4;        // 128 KiB
static constexpr size_t OFF_SC = OFF_MC + SZ_MS;
static constexpr size_t OFF_T = OFF_SC + SZ_MS;
static constexpr size_t OFF_END = OFF_T + (size_t)BHN * 4096 * 2;     // ~105 MiB

extern "C" void kernel_launch(void* const* d_in, const int* in_sizes, int n_in,
                              void* d_out, int out_size, void* d_ws, size_t ws_size,
                              hipStream_t stream) {
  const float* x = (const float*)d_in[0];
  const float* Wqkv = (const float*)d_in[1];
  const float* bqkv = (const float*)d_in[2];
  const float* Wproj = (const float*)d_in[3];
  const float* bproj = (const float*)d_in[4];
  float* out = (float*)d_out;
  char* ws = (char*)d_ws;
  if (ws_size < OFF_END) {  // diagnostic: absmax ~= 1 next round means ws too small
    ws_too_small_sentinel<<<1, 64, 0, stream>>>(out);
    return;
  }

  u16* qb = (u16*)(ws + OFF_Q);
  u16* kb = (u16*)(ws + OFF_K);
  u16* vb = (u16*)(ws + OFF_V);
  float* Fp = (float*)(ws + OFF_FP);
  float* Mc = (float*)(ws + OFF_MC);
  float* Sc = (float*)(ws + OFF_SC);
  u16* Tt = (u16*)(ws + OFF_T);
  u16* attn = (u16*)(ws + OFF_V);  // alias: v dead after fpart

  gemm_bt<0><<<dim3(256, 12), 256, 0, stream>>>(x, nullptr, Wqkv, bqkv, qb, kb, vb, nullptr);
  fpart<<<dim3(NCHUNK, BHN), 256, 0, stream>>>(qb, kb, vb, Fp, Mc, Sc);
  newton_t<<<dim3(BHN), 256, 0, stream>>>(qb, kb, Fp, Mc, Sc, Tt);
  attn_out_k<<<dim3(32, BHN), 256, 0, stream>>>(qb, kb, Tt, attn);
  gemm_bt<1><<<dim3(256, 4), 256, 0, stream>>>(nullptr, attn, Wproj, bproj, nullptr, nullptr, nullptr, out);
}

// Round 6
// 422.002 us; speedup vs baseline: 1.8112x; 1.2218x over previous
//
#include <hip/hip_runtime.h>

typedef unsigned short u16;
typedef unsigned int u32;

typedef __bf16 v8bf __attribute__((ext_vector_type(8)));
typedef float v4f __attribute__((ext_vector_type(4)));

#define N_TOK 8192
#define CDIM 512
#define HEADS 8
#define HD 64
#define LM 64
#define LSTRIDE 128
#define BHN 32
#define NCHUNK 16
#define SCALE 0.125f

__device__ __forceinline__ float b2f(u16 u) { return __uint_as_float(((u32)u) << 16); }
__device__ __forceinline__ u16 f2bf(float f) {
  u32 u = __float_as_uint(f);
  u += 0x7fffu + ((u >> 16) & 1u);
  return (u16)(u >> 16);
}

// ---------------------------------------------------------------------------
// fp32 -> bf16 cast, 8 elems/thread, fully coalesced.
// ---------------------------------------------------------------------------
__global__ __launch_bounds__(256) void cast_bf16(const float* __restrict__ src,
                                                 u16* __restrict__ dst, int n8) {
  int i = blockIdx.x * 256 + threadIdx.x;
  if (i >= n8) return;
  const float4* s = (const float4*)src;
  float4 a = s[(size_t)i * 2], b = s[(size_t)i * 2 + 1];
  uint4 o;
  o.x = (u32)f2bf(a.x) | ((u32)f2bf(a.y) << 16);
  o.y = (u32)f2bf(a.z) | ((u32)f2bf(a.w) << 16);
  o.z = (u32)f2bf(b.x) | ((u32)f2bf(b.y) << 16);
  o.w = (u32)f2bf(b.z) | ((u32)f2bf(b.w) << 16);
  *(uint4*)(dst + (size_t)i * 8) = o;
}

// ---------------------------------------------------------------------------
// GEMM: C[m][n] = sum_k A[m][k]*B[n][k] + bias[n]   (A,B bf16 K-contig)
// MODE 0: scatter bf16 to q/k/v [bh][n][d]; MODE 1: fp32 row-major out.
// 128x128 tile, BK=32, pure uint4 staging (no cast VALU), LDS stride 40
// (pads the 8-way b128 frag-read conflict away).
// ---------------------------------------------------------------------------
template <int MODE>
__global__ __launch_bounds__(256) void gemm_bt(const u16* __restrict__ A,
                                               const u16* __restrict__ Bm,
                                               const float* __restrict__ bias,
                                               u16* __restrict__ qo,
                                               u16* __restrict__ ko,
                                               u16* __restrict__ vo,
                                               float* __restrict__ outp) {
  __shared__ u16 As[128 * 40];
  __shared__ u16 Bs[128 * 40];
  const int K = 512;
  const int m0 = blockIdx.x * 128;
  const int n0 = blockIdx.y * 128;
  const int t = threadIdx.x;
  const int lane = t & 63, w = t >> 6;
  const int wm = w >> 1, wn = w & 1;
  const int quad = lane >> 4, lrow = lane & 15;

  v4f acc[4][4];
#pragma unroll
  for (int i = 0; i < 4; ++i)
#pragma unroll
    for (int j = 0; j < 4; ++j)
#pragma unroll
      for (int r = 0; r < 4; ++r) acc[i][j][r] = 0.f;

  for (int kt = 0; kt < K; kt += 32) {
    __syncthreads();
#pragma unroll
    for (int p = 0; p < 2; ++p) {
      int lin = p * 256 + t;
      int row = lin >> 2, c8 = (lin & 3) * 8;
      *(uint4*)&As[row * 40 + c8] = *(const uint4*)(A + (size_t)(m0 + row) * K + kt + c8);
      *(uint4*)&Bs[row * 40 + c8] = *(const uint4*)(Bm + (size_t)(n0 + row) * K + kt + c8);
    }
    __syncthreads();
    v8bf af[4], bf[4];
#pragma unroll
    for (int ti = 0; ti < 4; ++ti)
      af[ti] = *(const v8bf*)&As[(wm * 64 + ti * 16 + lrow) * 40 + quad * 8];
#pragma unroll
    for (int tj = 0; tj < 4; ++tj)
      bf[tj] = *(const v8bf*)&Bs[(wn * 64 + tj * 16 + lrow) * 40 + quad * 8];
#pragma unroll
    for (int ti = 0; ti < 4; ++ti)
#pragma unroll
      for (int tj = 0; tj < 4; ++tj)
        acc[ti][tj] = __builtin_amdgcn_mfma_f32_16x16x32_bf16(af[ti], bf[tj], acc[ti][tj], 0, 0, 0);
  }

  // epilogue: D layout col=lane&15, row=quad*4+reg (m89/m91-verified)
#pragma unroll
  for (int ti = 0; ti < 4; ++ti) {
#pragma unroll
    for (int tj = 0; tj < 4; ++tj) {
      int gn = n0 + wn * 64 + tj * 16 + lrow;
      float bv = bias[gn];
#pragma unroll
      for (int r = 0; r < 4; ++r) {
        int gm = m0 + wm * 64 + ti * 16 + quad * 4 + r;
        float val = acc[ti][tj][r] + bv;
        if (MODE == 0) {
          int tt = gn >> 9;          // 0=q 1=k 2=v
          int h = (gn >> 6) & 7;
          int d = gn & 63;
          int b = gm >> 13;
          int n = gm & 8191;
          size_t di = ((size_t)(b * HEADS + h) * N_TOK + n) * HD + d;
          u16* dst = (tt == 0) ? qo : (tt == 1) ? ko : vo;
          dst[di] = f2bf(val);
        } else {
          outp[(size_t)gm * CDIM + gn] = val;
        }
      }
    }
  }
}

// ---------------------------------------------------------------------------
// Fused kernel_3 chunk: online-softmax over j-chunk of 512, emits Fp, Mc, Sc.
// R5: transposed LDS layouts so all hot-loop accesses are float4/float2:
//   qlmT[d][i] (f4 read), ksT[d][j] (f2 read), PsT[j][i] (f4 w+r), vs[j][d] (f4).
// Same math, same accumulation order as R4.
// ---------------------------------------------------------------------------
__global__ __launch_bounds__(256) void fpart(const u16* __restrict__ qb,
                                             const u16* __restrict__ kb,
                                             const u16* __restrict__ vb,
                                             float* __restrict__ Fp,
                                             float* __restrict__ Mc,
                                             float* __restrict__ Sc) {
  __shared__ float qlmT[64 * 68];  // [d][i]
  __shared__ float ksT[64 * 36];   // [d][j]
  __shared__ float vs[32 * 68];    // [j][d]
  __shared__ float PsT[32 * 68];   // [j][i]
  __shared__ float ms[64], ss[64], alphas[64], betas[64];
  const int jc = blockIdx.x, bh = blockIdx.y;
  const int t = threadIdx.x;
  const int ti = t >> 4, tj = t & 15;   // rows i=ti*4+a; S cols j=tj*2+b; F cols d=tj*4+b

#pragma unroll
  for (int p = 0; p < 16; ++p) {
    int idx = p * 256 + t;
    int i = idx >> 6, d = idx & 63;
    qlmT[d * 68 + i] = b2f(qb[((size_t)bh * N_TOK + i * LSTRIDE) * HD + d]);
  }
  if (t < 64) { ms[t] = -3.0e38f; ss[t] = 0.f; }

  float F[4][4];
#pragma unroll
  for (int a = 0; a < 4; ++a)
#pragma unroll
    for (int b = 0; b < 4; ++b) F[a][b] = 0.f;

  for (int st = 0; st < 16; ++st) {
    __syncthreads();
#pragma unroll
    for (int p = 0; p < 8; ++p) {
      int idx = p * 256 + t;
      int j = idx >> 6, d = idx & 63;
      size_t g = ((size_t)bh * N_TOK + jc * 512 + st * 32 + j) * HD + d;
      ksT[d * 36 + j] = b2f(kb[g]);
      vs[j * 68 + d] = b2f(vb[g]);
    }
    __syncthreads();
    float S[4][2];
#pragma unroll
    for (int a = 0; a < 4; ++a)
#pragma unroll
      for (int b = 0; b < 2; ++b) S[a][b] = 0.f;
    for (int d = 0; d < 64; ++d) {
      float4 qa = *(const float4*)&qlmT[d * 68 + ti * 4];
      float2 kv = *(const float2*)&ksT[d * 36 + tj * 2];
      S[0][0] += qa.x * kv.x; S[0][1] += qa.x * kv.y;
      S[1][0] += qa.y * kv.x; S[1][1] += qa.y * kv.y;
      S[2][0] += qa.z * kv.x; S[2][1] += qa.z * kv.y;
      S[3][0] += qa.w * kv.x; S[3][1] += qa.w * kv.y;
    }
    float msub[4], rsum[4];
    float P0[4], P1[4];
#pragma unroll
    for (int a = 0; a < 4; ++a) {
      S[a][0] *= SCALE; S[a][1] *= SCALE;
      float m = fmaxf(S[a][0], S[a][1]);
#pragma unroll
      for (int off = 8; off; off >>= 1) m = fmaxf(m, __shfl_xor(m, off));
      msub[a] = m;
      float p0 = expf(S[a][0] - m), p1 = expf(S[a][1] - m);
      P0[a] = p0; P1[a] = p1;
      float s = p0 + p1;
#pragma unroll
      for (int off = 8; off; off >>= 1) s += __shfl_xor(s, off);
      rsum[a] = s;
    }
    {
      float4 w0 = {P0[0], P0[1], P0[2], P0[3]};
      float4 w1 = {P1[0], P1[1], P1[2], P1[3]};
      *(float4*)&PsT[(tj * 2 + 0) * 68 + ti * 4] = w0;
      *(float4*)&PsT[(tj * 2 + 1) * 68 + ti * 4] = w1;
    }
    if (tj == 0) {
#pragma unroll
      for (int a = 0; a < 4; ++a) {
        int i = ti * 4 + a;
        float mo = ms[i];
        float mn = fmaxf(mo, msub[a]);
        float alpha = expf(mo - mn);
        float beta = expf(msub[a] - mn);
        ms[i] = mn;
        ss[i] = ss[i] * alpha + beta * rsum[a];
        alphas[i] = alpha;
        betas[i] = beta;
      }
    }
    __syncthreads();
    float tmp[4][4];
#pragma unroll
    for (int a = 0; a < 4; ++a)
#pragma unroll
      for (int b = 0; b < 4; ++b) tmp[a][b] = 0.f;
    for (int jj = 0; jj < 32; ++jj) {
      float4 pa = *(const float4*)&PsT[jj * 68 + ti * 4];
      float4 vv = *(const float4*)&vs[jj * 68 + tj * 4];
      float paf[4] = {pa.x, pa.y, pa.z, pa.w};
      float vvf[4] = {vv.x, vv.y, vv.z, vv.w};
#pragma unroll
      for (int a = 0; a < 4; ++a)
#pragma unroll
        for (int b = 0; b < 4; ++b) tmp[a][b] += paf[a] * vvf[b];
    }
#pragma unroll
    for (int a = 0; a < 4; ++a) {
      int i = ti * 4 + a;
      float al = alphas[i], be = betas[i];
#pragma unroll
      for (int b = 0; b < 4; ++b) F[a][b] = F[a][b] * al + be * tmp[a][b];
    }
  }

  size_t base = (size_t)(bh * NCHUNK + jc) * 4096;
#pragma unroll
  for (int a = 0; a < 4; ++a)
#pragma unroll
    for (int b = 0; b < 4; ++b)
      Fp[base + (ti * 4 + a) * 64 + tj * 4 + b] = F[a][b];
  __syncthreads();
  if (t < 64) {
    Mc[(bh * NCHUNK + jc) * 64 + t] = ms[t];
    Sc[(bh * NCHUNK + jc) * 64 + t] = ss[t];
  }
}

// ---------------------------------------------------------------------------
// Per-(b,h): kernel_2 softmax, Newton-Schulz inverse, chunk combine, T = Z@F.
// Epilogue writes Tt = T^T bf16 [bh][d][j] for the MFMA attn_out. (unchanged)
// ---------------------------------------------------------------------------
__global__ __launch_bounds__(256) void newton_t(const u16* __restrict__ qb,
                                                const u16* __restrict__ kb,
                                                const float* __restrict__ Fp,
                                                const float* __restrict__ Mc,
                                                const float* __restrict__ Sc,
                                                u16* __restrict__ Tt) {
  __shared__ float Ms[4096];
  __shared__ float Z0s[4096];
  __shared__ float Ws[4096];
  __shared__ float Xs[4096];
  const int bh = blockIdx.x;
  const int t = threadIdx.x;
  const int lane = t & 63, w = t >> 6;
  const int ti = t >> 4, tj = t & 15;

#pragma unroll
  for (int p = 0; p < 16; ++p) {
    int idx = p * 256 + t;
    int i = idx >> 6, d = idx & 63;
    Ws[idx] = b2f(qb[((size_t)bh * N_TOK + i * LSTRIDE) * HD + d]);
    Xs[d * 64 + i] = b2f(kb[((size_t)bh * N_TOK + i * LSTRIDE) * HD + d]);
  }
  __syncthreads();

  {
    float a2[4][4];
#pragma unroll
    for (int a = 0; a < 4; ++a)
#pragma unroll
      for (int b = 0; b < 4; ++b) a2[a][b] = 0.f;
    for (int d = 0; d < 64; ++d) {
      float qa[4], kv[4];
#pragma unroll
      for (int a = 0; a < 4; ++a) qa[a] = Ws[(ti * 4 + a) * 64 + d];
#pragma unroll
      for (int b = 0; b < 4; ++b) kv[b] = Xs[d * 64 + tj * 4 + b];
#pragma unroll
      for (int a = 0; a < 4; ++a)
#pragma unroll
        for (int b = 0; b < 4; ++b) a2[a][b] += qa[a] * kv[b];
    }
    __syncthreads();
#pragma unroll
    for (int a = 0; a < 4; ++a)
#pragma unroll
      for (int b = 0; b < 4; ++b) Ms[(ti * 4 + a) * 64 + tj * 4 + b] = a2[a][b] * SCALE;
  }
  __syncthreads();

  for (int rr = 0; rr < 16; ++rr) {
    int i = w * 16 + rr;
    float vv = Ms[i * 64 + lane];
    float m = vv;
#pragma unroll
    for (int off = 32; off; off >>= 1) m = fmaxf(m, __shfl_xor(m, off));
    float e = expf(vv - m);
    float s = e;
#pragma unroll
    for (int off = 32; off; off >>= 1) s += __shfl_xor(s, off);
    Ms[i * 64 + lane] = e / s;
  }
  __syncthreads();

  float loc = 0.f;
#pragma unroll
  for (int p = 0; p < 16; ++p) {
    float v = Ms[p * 256 + t];
    loc += v * v;
  }
#pragma unroll
  for (int off = 32; off; off >>= 1) loc += __shfl_xor(loc, off);
  if (lane == 0) Z0s[w] = loc;
  __syncthreads();
  float fro = fmaxf(sqrtf(Z0s[0] + Z0s[1] + Z0s[2] + Z0s[3]), 1e-6f);
  float invden = 1.0f / (fro * fro);
  __syncthreads();

#pragma unroll
  for (int p = 0; p < 16; ++p) {
    int idx = p * 256 + t;
    int i = idx >> 6, j = idx & 63;
    Z0s[j * 64 + i] = Ms[idx] * invden;
  }
  __syncthreads();

  float* Z = Z0s;
  float* Zn = Xs;
  for (int it = 0; it < 6; ++it) {
    {  // Ws = Z @ M
      float a2[4][4];
#pragma unroll
      for (int a = 0; a < 4; ++a)
#pragma unroll
        for (int b = 0; b < 4; ++b) a2[a][b] = 0.f;
      for (int tt = 0; tt < 64; ++tt) {
        float za[4], mb[4];
#pragma unroll
        for (int a = 0; a < 4; ++a) za[a] = Z[(ti * 4 + a) * 64 + tt];
#pragma unroll
        for (int b = 0; b < 4; ++b) mb[b] = Ms[tt * 64 + tj * 4 + b];
#pragma unroll
        for (int a = 0; a < 4; ++a)
#pragma unroll
          for (int b = 0; b < 4; ++b) a2[a][b] += za[a] * mb[b];
      }
#pragma unroll
      for (int a = 0; a < 4; ++a)
#pragma unroll
        for (int b = 0; b < 4; ++b) Ws[(ti * 4 + a) * 64 + tj * 4 + b] = a2[a][b];
    }
    __syncthreads();
    {  // Zn = 2Z - Ws @ Z
      float a2[4][4];
#pragma unroll
      for (int a = 0; a < 4; ++a)
#pragma unroll
        for (int b = 0; b < 4; ++b) a2[a][b] = 0.f;
      for (int tt = 0; tt < 64; ++tt) {
        float wa[4], zb[4];
#pragma unroll
        for (int a = 0; a < 4; ++a) wa[a] = Ws[(ti * 4 + a) * 64 + tt];
#pragma unroll
        for (int b = 0; b < 4; ++b) zb[b] = Z[tt * 64 + tj * 4 + b];
#pragma unroll
        for (int a = 0; a < 4; ++a)
#pragma unroll
          for (int b = 0; b < 4; ++b) a2[a][b] += wa[a] * zb[b];
      }
#pragma unroll
      for (int a = 0; a < 4; ++a)
#pragma unroll
        for (int b = 0; b < 4; ++b)
          Zn[(ti * 4 + a) * 64 + tj * 4 + b] =
              2.f * Z[(ti * 4 + a) * 64 + tj * 4 + b] - a2[a][b];
    }
    __syncthreads();
    float* tmp = Z; Z = Zn; Zn = tmp;
  }

  float* wts = Ms;  // Ms dead -> chunk combine weights [jc][i]
  if (t < 64) {
    float M = -3.0e38f;
#pragma unroll
    for (int jc = 0; jc < NCHUNK; ++jc)
      M = fmaxf(M, Mc[(bh * NCHUNK + jc) * 64 + t]);
    float S = 0.f;
#pragma unroll
    for (int jc = 0; jc < NCHUNK; ++jc)
      S += expf(Mc[(bh * NCHUNK + jc) * 64 + t] - M) * Sc[(bh * NCHUNK + jc) * 64 + t];
    float invS = 1.0f / S;
#pragma unroll
    for (int jc = 0; jc < NCHUNK; ++jc)
      wts[jc * 64 + t] = expf(Mc[(bh * NCHUNK + jc) * 64 + t] - M) * invS;
  }
  __syncthreads();

#pragma unroll
  for (int p = 0; p < 16; ++p) {
    int idx = p * 256 + t;
    int i = idx >> 6;
    float sum = 0.f;
#pragma unroll
    for (int jc = 0; jc < NCHUNK; ++jc)
      sum += wts[jc * 64 + i] * Fp[(size_t)(bh * NCHUNK + jc) * 4096 + idx];
    Ws[idx] = sum;
  }
  __syncthreads();

  {
    float a2[4][4];
#pragma unroll
    for (int a = 0; a < 4; ++a)
#pragma unroll
      for (int b = 0; b < 4; ++b) a2[a][b] = 0.f;
    for (int tt = 0; tt < 64; ++tt) {
      float za[4], fb[4];
#pragma unroll
      for (int a = 0; a < 4; ++a) za[a] = Z[(ti * 4 + a) * 64 + tt];
#pragma unroll
      for (int b = 0; b < 4; ++b) fb[b] = Ws[tt * 64 + tj * 4 + b];
#pragma unroll
      for (int a = 0; a < 4; ++a)
#pragma unroll
        for (int b = 0; b < 4; ++b) a2[a][b] += za[a] * fb[b];
    }
#pragma unroll
    for (int a = 0; a < 4; ++a)
#pragma unroll
      for (int b = 0; b < 4; ++b)
        Tt[(size_t)bh * 4096 + (size_t)(tj * 4 + b) * 64 + (ti * 4 + a)] = f2bf(a2[a][b]);
  }
}

// ---------------------------------------------------------------------------
// MFMA attn_out (unchanged from R4): S^T = klm@q^T, in-register softmax,
// P via per-wave swizzled LDS, out = P@Tt.
// ---------------------------------------------------------------------------
__global__ __launch_bounds__(256) void attn_out_k(const u16* __restrict__ qb,
                                                  const u16* __restrict__ kb,
                                                  const u16* __restrict__ Tt,
                                                  u16* __restrict__ ao) {
  __shared__ __align__(16) u16 Pl[4][1024];
  const int bh = blockIdx.y;
  const int b = bh >> 3, h = bh & 7;
  const int t = threadIdx.x;
  const int lane = t & 63, w = t >> 6;
  const int col = lane & 15, quad = lane >> 4;
  const int rot = (col & 7) * 8;

  v8bf kfr[4][2], tfr[4][2];
#pragma unroll
  for (int tj = 0; tj < 4; ++tj)
#pragma unroll
    for (int kh = 0; kh < 2; ++kh)
      kfr[tj][kh] = *(const v8bf*)(kb + ((size_t)bh * N_TOK + (size_t)(tj * 16 + col) * LSTRIDE) * HD + kh * 32 + quad * 8);
#pragma unroll
  for (int td = 0; td < 4; ++td)
#pragma unroll
    for (int jh = 0; jh < 2; ++jh)
      tfr[td][jh] = *(const v8bf*)(Tt + (size_t)bh * 4096 + (size_t)(td * 16 + col) * 64 + jh * 32 + quad * 8);

  u16* Pw = &Pl[w][0];

  for (int tile = 0; tile < 4; ++tile) {
    const int n0 = blockIdx.x * 256 + w * 64 + tile * 16;
    v8bf qf[2];
#pragma unroll
    for (int kh = 0; kh < 2; ++kh)
      qf[kh] = *(const v8bf*)(qb + ((size_t)bh * N_TOK + n0 + col) * HD + kh * 32 + quad * 8);

    v4f S[4];
#pragma unroll
    for (int tj = 0; tj < 4; ++tj) {
#pragma unroll
      for (int r = 0; r < 4; ++r) S[tj][r] = 0.f;
#pragma unroll
      for (int kh = 0; kh < 2; ++kh)
        S[tj] = __builtin_amdgcn_mfma_f32_16x16x32_bf16(kfr[tj][kh], qf[kh], S[tj], 0, 0, 0);
    }

    float mx = -3.0e38f;
#pragma unroll
    for (int tj = 0; tj < 4; ++tj)
#pragma unroll
      for (int r = 0; r < 4; ++r) {
        S[tj][r] *= SCALE;
        mx = fmaxf(mx, S[tj][r]);
      }
    mx = fmaxf(mx, __shfl_xor(mx, 16));
    mx = fmaxf(mx, __shfl_xor(mx, 32));
    float sum = 0.f;
#pragma unroll
    for (int tj = 0; tj < 4; ++tj)
#pragma unroll
      for (int r = 0; r < 4; ++r) {
        S[tj][r] = __expf(S[tj][r] - mx);
        sum += S[tj][r];
      }
    sum += __shfl_xor(sum, 16);
    sum += __shfl_xor(sum, 32);
    float inv = 1.0f / sum;

#pragma unroll
    for (int tj = 0; tj < 4; ++tj) {
      u32 lo = (u32)f2bf(S[tj][0] * inv) | ((u32)f2bf(S[tj][1] * inv) << 16);
      u32 hi = (u32)f2bf(S[tj][2] * inv) | ((u32)f2bf(S[tj][3] * inv) << 16);
      uint2 pk = {lo, hi};
      *(uint2*)&Pw[col * 64 + ((tj * 16 + quad * 4 + rot) & 63)] = pk;
    }
    v8bf pf[2];
#pragma unroll
    for (int jh = 0; jh < 2; ++jh)
      pf[jh] = *(const v8bf*)&Pw[col * 64 + ((jh * 32 + quad * 8 + rot) & 63)];

    v4f O[4];
#pragma unroll
    for (int td = 0; td < 4; ++td) {
#pragma unroll
      for (int r = 0; r < 4; ++r) O[td][r] = 0.f;
#pragma unroll
      for (int jh = 0; jh < 2; ++jh)
        O[td] = __builtin_amdgcn_mfma_f32_16x16x32_bf16(pf[jh], tfr[td][jh], O[td], 0, 0, 0);
    }
#pragma unroll
    for (int td = 0; td < 4; ++td)
#pragma unroll
      for (int r = 0; r < 4; ++r) {
        int n = n0 + quad * 4 + r;
        ao[((size_t)(b * N_TOK + n)) * CDIM + h * HD + td * 16 + col] = f2bf(O[td][r]);
      }
  }
}

__global__ void ws_too_small_sentinel(float* out) {
  if (threadIdx.x == 0 && blockIdx.x == 0) out[0] = 1.0f;
}

// ---------------------------------------------------------------------------
// Workspace: q/k/v bf16 (96 MiB), Fp fp32 8 MiB, Mc/Sc/Tt small, Wqkv/Wproj
// bf16 casts (+2 MiB). x_bf16 lives in d_out (dead until gemm1). ~107 MiB.
// ---------------------------------------------------------------------------
static constexpr size_t SZ_QKV = (size_t)BHN * N_TOK * HD * 2;        // 32 MiB
static constexpr size_t OFF_Q = 0;
static constexpr size_t OFF_K = OFF_Q + SZ_QKV;
static constexpr size_t OFF_V = OFF_K + SZ_QKV;
static constexpr size_t OFF_FP = OFF_V + SZ_QKV;
static constexpr size_t SZ_FP = (size_t)BHN * NCHUNK * 4096 * 4;      // 8 MiB
static constexpr size_t OFF_MC = OFF_FP + SZ_FP;
static constexpr size_t SZ_MS = (size_t)BHN * NCHUNK * 64 * 4;        // 128 KiB
static constexpr size_t OFF_SC = OFF_MC + SZ_MS;
static constexpr size_t OFF_T = OFF_SC + SZ_MS;
static constexpr size_t OFF_WQ = OFF_T + (size_t)BHN * 4096 * 2;      // Tt 256 KiB
static constexpr size_t OFF_WP = OFF_WQ + (size_t)3 * CDIM * CDIM * 2;  // Wqkv bf16 1.5 MiB
static constexpr size_t OFF_END = OFF_WP + (size_t)CDIM * CDIM * 2;     // +0.5 MiB

extern "C" void kernel_launch(void* const* d_in, const int* in_sizes, int n_in,
                              void* d_out, int out_size, void* d_ws, size_t ws_size,
                              hipStream_t stream) {
  const float* x = (const float*)d_in[0];
  const float* Wqkv = (const float*)d_in[1];
  const float* bqkv = (const float*)d_in[2];
  const float* Wproj = (const float*)d_in[3];
  const float* bproj = (const float*)d_in[4];
  float* out = (float*)d_out;
  char* ws = (char*)d_ws;
  if (ws_size < OFF_END) {
    ws_too_small_sentinel<<<1, 64, 0, stream>>>(out);
    return;
  }

  u16* qb = (u16*)(ws + OFF_Q);
  u16* kb = (u16*)(ws + OFF_K);
  u16* vb = (u16*)(ws + OFF_V);
  float* Fp = (float*)(ws + OFF_FP);
  float* Mc = (float*)(ws + OFF_MC);
  float* Sc = (float*)(ws + OFF_SC);
  u16* Tt = (u16*)(ws + OFF_T);
  u16* Wqb = (u16*)(ws + OFF_WQ);
  u16* Wpb = (u16*)(ws + OFF_WP);
  u16* attn = (u16*)(ws + OFF_V);   // alias: v dead after fpart
  u16* xb = (u16*)d_out;            // alias: d_out scratch, dead before gemm<1> writes

  cast_bf16<<<8192, 256, 0, stream>>>(x, xb, 2097152);          // 16.78M elems
  cast_bf16<<<384, 256, 0, stream>>>(Wqkv, Wqb, 98304);         // 786K
  cast_bf16<<<128, 256, 0, stream>>>(Wproj, Wpb, 32768);        // 262K
  gemm_bt<0><<<dim3(256, 12), 256, 0, stream>>>(xb, Wqb, bqkv, qb, kb, vb, nullptr);
  fpart<<<dim3(NCHUNK, BHN), 256, 0, stream>>>(qb, kb, vb, Fp, Mc, Sc);
  newton_t<<<dim3(BHN), 256, 0, stream>>>(qb, kb, Fp, Mc, Sc, Tt);
  attn_out_k<<<dim3(32, BHN), 256, 0, stream>>>(qb, kb, Tt, attn);
  gemm_bt<1><<<dim3(256, 4), 256, 0, stream>>>(attn, Wpb, bproj, nullptr, nullptr, nullptr, out);
}